// Round 21
// baseline (82.956 us; speedup 1.0000x reference)
//
#include <hip/hip_runtime.h>
#include <math.h>

#define NQ       8
#define NLAYERS  4
#define OUTC     8
#define BATCH    128
#define LEN      512
#define OUTL     505
#define NPATCH   (BATCH * OUTL)      // 64640
#define BM       64
#define NBLK     (NPATCH / BM)       // 1010
#define BLK_PER_CH 1010

typedef __attribute__((ext_vector_type(8))) short bf16x8;
typedef __attribute__((ext_vector_type(4))) float f32x4;

__device__ __forceinline__ ushort to_bf16(float f) {
    union { float f; unsigned int u; } v; v.f = f;
    unsigned int b = v.u + 0x7FFFu + ((v.u >> 16) & 1u);
    return (ushort)(b >> 16);
}

// packed f32x2 -> bf16x2 (RTNE)
__device__ __forceinline__ unsigned pk_bf16(float lo, float hi) {
    unsigned r;
    asm("v_cvt_pk_bf16_f32 %0, %1, %2" : "=v"(r) : "v"(lo), "v"(hi));
    return r;
}

// quad_perm lane swaps: xor1 -> 0xB1, xor2 -> 0x4E
template <int CTRL>
__device__ __forceinline__ float dpp_xor(float x) {
    int i = __float_as_int(x);
    int r = __builtin_amdgcn_update_dpp(0, i, CTRL, 0xF, 0xF, true);
    return __int_as_float(r);
}

// v += row_ror<N>(v): sum-rotation within 16-lane row, pure VALU (verified R9+)
template <int N>
__device__ __forceinline__ float ror_add(float x) {
    int i = __float_as_int(x);
    int r = __builtin_amdgcn_update_dpp(0, i, 0x120 + N, 0xF, 0xF, true);
    return x + __int_as_float(r);
}

// 4-layer circuit on the 4-lane x 64-reg state layout (verified R5).
__device__ __forceinline__ void run_layers(float st[64], const float* wk, int b0, int b7) {
#pragma unroll 1
    for (int layer = 0; layer < NLAYERS; ++layer) {
        float wc[NQ], wsn[NQ];
#pragma unroll
        for (int q = 0; q < NQ; ++q) {
            float half = 0.5f * wk[layer * NQ + q];
            wc[q]  = __cosf(half);
            wsn[q] = __sinf(half);
        }
        {
            const float sg = b0 ? wsn[0] : -wsn[0];
#pragma unroll
            for (int r = 0; r < 64; ++r) {
                float p = dpp_xor<0x4E>(st[r]);
                st[r] = fmaf(wc[0], st[r], sg * p);
            }
        }
#pragma unroll
        for (int q = 1; q <= 6; ++q) {
            const int m = 1 << (6 - q);
#pragma unroll
            for (int r = 0; r < 64; ++r) {
                if (r & m) continue;
                float a0 = st[r], a1 = st[r + m];
                st[r]     = fmaf(wc[q], a0, -wsn[q] * a1);
                st[r + m] = fmaf(wc[q], a1,  wsn[q] * a0);
            }
        }
        {
            const float sg = b7 ? wsn[7] : -wsn[7];
#pragma unroll
            for (int r = 0; r < 64; ++r) {
                float p = dpp_xor<0xB1>(st[r]);
                st[r] = fmaf(wc[7], st[r], sg * p);
            }
        }
#pragma unroll
        for (int r = 0; r < 32; ++r) {
            float t0 = st[r], t1 = st[r + 32];
            st[r]      = b0 ? t1 : t0;
            st[r + 32] = b0 ? t0 : t1;
        }
#pragma unroll
        for (int q = 1; q <= 5; ++q) {
            const int cm = 1 << (6 - q);
            const int tm = 1 << (5 - q);
#pragma unroll
            for (int r = 0; r < 64; ++r) {
                if ((r & cm) && !(r & tm)) {
                    float t = st[r]; st[r] = st[r + tm]; st[r + tm] = t;
                }
            }
        }
#pragma unroll
        for (int r = 1; r < 64; r += 2) st[r] = dpp_xor<0xB1>(st[r]);
    }
}

// ---------------- Kernel 1: build W2 in direct-fragment layout (verified R9-R20).
// ushort index(ch, i, j) = ((ph*4 + (i>>6))*4 + ((i>>4)&3))*512
//                          + (((j>>3)&3)*16 + (i&15))*8 + (j&7),  ph = ch*8 + (j>>5)
__global__ __launch_bounds__(256) void build_m(const float* __restrict__ w,
                                               ushort* __restrict__ W2) {
    const int tid  = threadIdx.x;
    const int lane = tid & 63;
    const int k    = blockIdx.x >> 2;
    const int j    = ((blockIdx.x & 3) << 6) | (tid >> 2);   // basis column = K index
    const int b0 = (lane >> 1) & 1;
    const int b7 = lane & 1;

    float st[64];
    const int r0 = (j >> 1) & 63;
    const bool mine = (b0 == ((j >> 7) & 1)) && (b7 == (j & 1));
#pragma unroll
    for (int r = 0; r < 64; ++r) st[r] = (mine && r == r0) ? 1.0f : 0.0f;

    run_layers(st, w + k * (NLAYERS * NQ), b0, b7);

    const int ph = (k << 3) | (j >> 5);
    const int gj = (j >> 3) & 3;
    const int je = j & 7;
#pragma unroll
    for (int r = 0; r < 64; ++r) {
        int i  = (b0 << 7) | (r << 1) | b7;
        size_t idx = (size_t)((ph * 4 + (i >> 6)) * 4 + ((i >> 4) & 3)) * 512
                   + (gj * 16 + (i & 15)) * 8 + je;
        W2[idx] = to_bf16(st[r]);
    }
}

// ---------------- Kernel 2: R20 base + s_setprio(1) around each phase's MFMA
// cluster (T5). Prerequisite role-diversity exists via per-wave phase rotation.
__global__ __launch_bounds__(256, 2) void qconv_mfma(const float* __restrict__ x,
                                                     const ushort* __restrict__ W2,
                                                     float* __restrict__ out) {
    __shared__ ushort Alds[64 * 256];        // 32 KB A tile (swizzled 16B chunks)
    __shared__ float  red[4 * 4 * 64];       // 4 KB cross-wave partials (4 local ch)

    const int tid  = threadIdx.x;
    const int lane = tid & 63;
    const int wv   = tid >> 6;
    const int u    = lane & 15;
    const int g    = lane >> 4;
    const int bid  = blockIdx.x;
    const int pblk = bid >> 1;
    const int cb   = (bid & 1) * 4;          // channel base: 0 or 4
    const int pbase = pblk * BM;
    const int c0   = pblk & 3;               // stagger offset within the 4 channels
    const int s0   = wv * 2;                 // per-wave K-phase rotation

    // per-lane B base (ushort units): + ph*8192 + ct*512
    const ushort* bbase = W2 + (size_t)wv * 2048 + lane * 8;

    // prologue: first visited phase ph = (cb+c0)*8 + s0
    uint4 breg[4];
#pragma unroll
    for (int ct = 0; ct < 4; ++ct)
        breg[ct] = *(const uint4*)(bbase + (size_t)((cb + c0) * 8 + s0) * 8192 + ct * 512);

    // ---- embed: lane embeds patch pbase+lane, j-quarter jb = wave index
    {
        const int row = lane;
        const int jb  = wv;
        const int p = pbase + row;
        const int b = p / OUTL, ol = p - b * OUTL;
        const float* xp = x + b * LEN + ol;
        float ec[NQ], es[NQ];
#pragma unroll
        for (int q = 0; q < NQ; ++q) {
            float half = xp[q] * 1.5707963267948966f;
            ec[q] = __cosf(half);
            es[q] = __sinf(half);
        }
        float st[64];
        st[0] = (jb & 2 ? es[0] : ec[0]) * (jb & 1 ? es[1] : ec[1]);
#pragma unroll
        for (int q = 2; q <= 7; ++q) {           // wires 2..7 -> j bits 5..0
            const int m = 1 << (7 - q);
#pragma unroll
            for (int jj = (1 << (q - 2)) - 1; jj >= 0; --jj) {
                float v = st[jj * 2 * m];
                st[jj * 2 * m + m] = v * es[q];
                st[jj * 2 * m]     = v * ec[q];
            }
        }
#pragma unroll
        for (int cc = 0; cc < 8; ++cc) {
            uint4 vv;
            vv.x = pk_bf16(st[cc * 8 + 0], st[cc * 8 + 1]);
            vv.y = pk_bf16(st[cc * 8 + 2], st[cc * 8 + 3]);
            vv.z = pk_bf16(st[cc * 8 + 4], st[cc * 8 + 5]);
            vv.w = pk_bf16(st[cc * 8 + 6], st[cc * 8 + 7]);
            int phys = ((jb * 8 + cc) ^ (row & 7)) & 31;
            *(uint4*)((char*)Alds + row * 512 + phys * 16) = vv;
        }
    }
    __syncthreads();

    const int pu = __builtin_popcount(u) & 1;
    const int pw = __builtin_popcount(wv) & 1;
    const float slane = ((pu ^ pw) & 1) ? -1.0f : 1.0f;

#pragma unroll 1
    for (int it = 0; it < 4; ++it) {
        const int c  = cb + ((it + c0) & 3);     // actual channel this iteration
        const int cn = cb + ((it + 1 + c0) & 3); // next channel in staggered order

        f32x4 acc[4][4];
#pragma unroll
        for (int a = 0; a < 4; ++a)
#pragma unroll
            for (int cq = 0; cq < 4; ++cq) acc[a][cq] = (f32x4){0.f, 0.f, 0.f, 0.f};

#pragma unroll
        for (int t = 0; t < 8; ++t) {
            const int sl = (s0 + t) & 7;         // rotated K-phase for this wave
            // MFMA cluster: boost wave priority while consuming A + breg (T5)
            __builtin_amdgcn_s_setprio(1);
#pragma unroll
            for (int rt = 0; rt < 4; ++rt) {
                int row = rt * 16 + u;
                int phys = ((sl * 4 + g) ^ (row & 7)) & 31;
                bf16x8 af = *(const bf16x8*)((const char*)Alds + row * 512 + phys * 16);
#pragma unroll
                for (int ct = 0; ct < 4; ++ct)
                    acc[rt][ct] = __builtin_amdgcn_mfma_f32_16x16x32_bf16(
                        af, *(bf16x8*)&breg[ct], acc[rt][ct], 0, 0, 0);
            }
            __builtin_amdgcn_s_setprio(0);
            // refill the slot for the next rotated phase (WAR-safe)
            const int phn = (t < 7) ? (c * 8 + ((s0 + t + 1) & 7)) : (cn * 8 + s0);
            if (!(it == 3 && t == 7)) {
#pragma unroll
                for (int ct = 0; ct < 4; ++ct)
                    breg[ct] = *(const uint4*)(bbase + (size_t)phn * 8192 + ct * 512);
            }
        }

        // epilogue: parity-grouped signed square (sign folded to one mul),
        // then DPP-rotation reduce over the 16-lane col group
#pragma unroll
        for (int rt = 0; rt < 4; ++rt) {
            f32x4 pe = acc[rt][0] * acc[rt][0];   // ct=0: popc even
            pe += acc[rt][3] * acc[rt][3];        // ct=3: popc even
            f32x4 po = acc[rt][1] * acc[rt][1];   // ct=1: popc odd
            po += acc[rt][2] * acc[rt][2];        // ct=2: popc odd
            f32x4 part = (pe - po) * slane;
            float v0 = part[0], v1 = part[1], v2 = part[2], v3 = part[3];
            v0 = ror_add<8>(ror_add<4>(ror_add<2>(ror_add<1>(v0))));
            v1 = ror_add<8>(ror_add<4>(ror_add<2>(ror_add<1>(v1))));
            v2 = ror_add<8>(ror_add<4>(ror_add<2>(ror_add<1>(v2))));
            v3 = ror_add<8>(ror_add<4>(ror_add<2>(ror_add<1>(v3))));
            if (u == 0) {
                f32x4 vv = (f32x4){v0, v1, v2, v3};
                *(f32x4*)&red[((c & 3) * 4 + wv) * 64 + rt * 16 + g * 4] = vv;
            }
        }
    }

    __syncthreads();
    // final: sum 4 wave-partials, store. 1 output/thread (4ch x 64 rows = 256)
    {
        int chl = tid >> 6, row = tid & 63;
        int ch = cb + chl;
        float o = red[(chl * 4 + 0) * 64 + row] + red[(chl * 4 + 1) * 64 + row] +
                  red[(chl * 4 + 2) * 64 + row] + red[(chl * 4 + 3) * 64 + row];
        int p = pbase + row;
        int b = p / OUTL, ol = p - b * OUTL;
        out[b * (OUTC * OUTL) + ch * OUTL + ol] = o;
    }
}

// ---------------- Fallback: verified direct simulator (213 us)
__global__ __launch_bounds__(256) void qconv_direct(const float* __restrict__ x,
                                                    const float* __restrict__ w,
                                                    float* __restrict__ out) {
    const int lane = threadIdx.x & 63;
    const int wave = threadIdx.x >> 6;
    const int bi   = blockIdx.x;
    const int k    = bi / BLK_PER_CH;
    const int pblk = bi % BLK_PER_CH;
    const int patch = pblk * 64 + wave * 16 + (lane >> 2);
    const int b0 = (lane >> 1) & 1;
    const int b7 = lane & 1;
    const int b  = patch / OUTL;
    const int ol = patch - b * OUTL;
    const float* xp = x + b * LEN + ol;

    float ec[NQ], es[NQ];
#pragma unroll
    for (int q = 0; q < NQ; ++q) {
        float half = xp[q] * 1.5707963267948966f;
        ec[q] = __cosf(half);
        es[q] = __sinf(half);
    }
    float st[64];
    st[0] = (b0 ? es[0] : ec[0]) * (b7 ? es[7] : ec[7]);
#pragma unroll
    for (int q = 1; q <= 6; ++q) {
        const int m = 1 << (6 - q);
#pragma unroll
        for (int j = (1 << (q - 1)) - 1; j >= 0; --j) {
            float v = st[j * 2 * m];
            st[j * 2 * m + m] = v * es[q];
            st[j * 2 * m]     = v * ec[q];
        }
    }
    run_layers(st, w + k * (NLAYERS * NQ), b0, b7);

    float accp = 0.0f, accm = 0.0f;
#pragma unroll
    for (int r = 0; r < 64; ++r) {
        if (__builtin_popcount(r) & 1) accm = fmaf(st[r], st[r], accm);
        else                           accp = fmaf(st[r], st[r], accp);
    }
    float v = accp - accm;
    if (b0 ^ b7) v = -v;
    v += dpp_xor<0xB1>(v);
    v += dpp_xor<0x4E>(v);
    if ((lane & 3) == 0) out[b * (OUTC * OUTL) + k * OUTL + ol] = v;
}

extern "C" void kernel_launch(void* const* d_in, const int* in_sizes, int n_in,
                              void* d_out, int out_size, void* d_ws, size_t ws_size,
                              hipStream_t stream) {
    const float* x = (const float*)d_in[0];   // (128,1,512) f32
    const float* w = (const float*)d_in[1];   // (8,32) f32
    float* out = (float*)d_out;               // (128,8,505) f32

    if (ws_size < (size_t)(8 * 256 * 256 * 2)) {
        qconv_direct<<<dim3(OUTC * BLK_PER_CH), 256, 0, stream>>>(x, w, out);
        return;
    }
    ushort* W2 = (ushort*)d_ws;               // 1 MB bf16, direct-fragment layout
    build_m<<<dim3(32), 256, 0, stream>>>(w, W2);
    qconv_mfma<<<dim3(NBLK * 2), 256, 0, stream>>>(x, W2, out);
}

// Round 22
// 81.013 us; speedup vs baseline: 1.0240x; 1.0240x over previous
//
#include <hip/hip_runtime.h>
#include <math.h>

#define NQ       8
#define NLAYERS  4
#define OUTC     8
#define BATCH    128
#define LEN      512
#define OUTL     505
#define NPATCH   (BATCH * OUTL)      // 64640
#define BM       64
#define NBLK     (NPATCH / BM)       // 1010
#define BLK_PER_CH 1010

typedef __attribute__((ext_vector_type(8))) short bf16x8;
typedef __attribute__((ext_vector_type(4))) float f32x4;

__device__ __forceinline__ ushort to_bf16(float f) {
    union { float f; unsigned int u; } v; v.f = f;
    unsigned int b = v.u + 0x7FFFu + ((v.u >> 16) & 1u);
    return (ushort)(b >> 16);
}

// packed f32x2 -> bf16x2 (RTNE)
__device__ __forceinline__ unsigned pk_bf16(float lo, float hi) {
    unsigned r;
    asm("v_cvt_pk_bf16_f32 %0, %1, %2" : "=v"(r) : "v"(lo), "v"(hi));
    return r;
}

// quad_perm lane swaps: xor1 -> 0xB1, xor2 -> 0x4E
template <int CTRL>
__device__ __forceinline__ float dpp_xor(float x) {
    int i = __float_as_int(x);
    int r = __builtin_amdgcn_update_dpp(0, i, CTRL, 0xF, 0xF, true);
    return __int_as_float(r);
}

// v += row_ror<N>(v): sum-rotation within 16-lane row, pure VALU (verified R9+)
template <int N>
__device__ __forceinline__ float ror_add(float x) {
    int i = __float_as_int(x);
    int r = __builtin_amdgcn_update_dpp(0, i, 0x120 + N, 0xF, 0xF, true);
    return x + __int_as_float(r);
}

// 4-layer circuit on the 4-lane x 64-reg state layout (verified R5).
__device__ __forceinline__ void run_layers(float st[64], const float* wk, int b0, int b7) {
#pragma unroll 1
    for (int layer = 0; layer < NLAYERS; ++layer) {
        float wc[NQ], wsn[NQ];
#pragma unroll
        for (int q = 0; q < NQ; ++q) {
            float half = 0.5f * wk[layer * NQ + q];
            wc[q]  = __cosf(half);
            wsn[q] = __sinf(half);
        }
        {
            const float sg = b0 ? wsn[0] : -wsn[0];
#pragma unroll
            for (int r = 0; r < 64; ++r) {
                float p = dpp_xor<0x4E>(st[r]);
                st[r] = fmaf(wc[0], st[r], sg * p);
            }
        }
#pragma unroll
        for (int q = 1; q <= 6; ++q) {
            const int m = 1 << (6 - q);
#pragma unroll
            for (int r = 0; r < 64; ++r) {
                if (r & m) continue;
                float a0 = st[r], a1 = st[r + m];
                st[r]     = fmaf(wc[q], a0, -wsn[q] * a1);
                st[r + m] = fmaf(wc[q], a1,  wsn[q] * a0);
            }
        }
        {
            const float sg = b7 ? wsn[7] : -wsn[7];
#pragma unroll
            for (int r = 0; r < 64; ++r) {
                float p = dpp_xor<0xB1>(st[r]);
                st[r] = fmaf(wc[7], st[r], sg * p);
            }
        }
#pragma unroll
        for (int r = 0; r < 32; ++r) {
            float t0 = st[r], t1 = st[r + 32];
            st[r]      = b0 ? t1 : t0;
            st[r + 32] = b0 ? t0 : t1;
        }
#pragma unroll
        for (int q = 1; q <= 5; ++q) {
            const int cm = 1 << (6 - q);
            const int tm = 1 << (5 - q);
#pragma unroll
            for (int r = 0; r < 64; ++r) {
                if ((r & cm) && !(r & tm)) {
                    float t = st[r]; st[r] = st[r + tm]; st[r + tm] = t;
                }
            }
        }
#pragma unroll
        for (int r = 1; r < 64; r += 2) st[r] = dpp_xor<0xB1>(st[r]);
    }
}

// ---------------- Kernel 1: build W2 in direct-fragment layout (verified R9-R19).
// ushort index(ch, i, j) = ((ph*4 + (i>>6))*4 + ((i>>4)&3))*512
//                          + (((j>>3)&3)*16 + (i&15))*8 + (j&7),  ph = ch*8 + (j>>5)
__global__ __launch_bounds__(256) void build_m(const float* __restrict__ w,
                                               ushort* __restrict__ W2) {
    const int tid  = threadIdx.x;
    const int lane = tid & 63;
    const int k    = blockIdx.x >> 2;
    const int j    = ((blockIdx.x & 3) << 6) | (tid >> 2);   // basis column = K index
    const int b0 = (lane >> 1) & 1;
    const int b7 = lane & 1;

    float st[64];
    const int r0 = (j >> 1) & 63;
    const bool mine = (b0 == ((j >> 7) & 1)) && (b7 == (j & 1));
#pragma unroll
    for (int r = 0; r < 64; ++r) st[r] = (mine && r == r0) ? 1.0f : 0.0f;

    run_layers(st, w + k * (NLAYERS * NQ), b0, b7);

    const int ph = (k << 3) | (j >> 5);
    const int gj = (j >> 3) & 3;
    const int je = j & 7;
#pragma unroll
    for (int r = 0; r < 64; ++r) {
        int i  = (b0 << 7) | (r << 1) | b7;
        size_t idx = (size_t)((ph * 4 + (i >> 6)) * 4 + ((i >> 4) & 3)) * 512
                   + (gj * 16 + (i & 15)) * 8 + je;
        W2[idx] = to_bf16(st[r]);
    }
}

// ---------------- Kernel 2: channel-split — 2020 blocks, each 64 patches x 4 channels.
// Best measured config (R19: 72.6 us). Ring-1 B, stagger, no rotation/setprio.
__global__ __launch_bounds__(256, 2) void qconv_mfma(const float* __restrict__ x,
                                                     const ushort* __restrict__ W2,
                                                     float* __restrict__ out) {
    __shared__ ushort Alds[64 * 256];        // 32 KB A tile (swizzled 16B chunks)
    __shared__ float  red[4 * 4 * 64];       // 4 KB cross-wave partials (4 local ch)

    const int tid  = threadIdx.x;
    const int lane = tid & 63;
    const int wv   = tid >> 6;
    const int u    = lane & 15;
    const int g    = lane >> 4;
    const int bid  = blockIdx.x;
    const int pblk = bid >> 1;
    const int cb   = (bid & 1) * 4;          // channel base: 0 or 4
    const int pbase = pblk * BM;
    const int c0   = pblk & 3;               // stagger offset within the 4 channels

    // per-lane B base (ushort units): + ph*8192 + ct*512
    const ushort* bbase = W2 + (size_t)wv * 2048 + lane * 8;

    // prologue: load first staggered phase ph = (cb+c0)*8  (offset (cb+c0)*65536)
    uint4 breg[4];
#pragma unroll
    for (int ct = 0; ct < 4; ++ct)
        breg[ct] = *(const uint4*)(bbase + (size_t)(cb + c0) * 65536 + ct * 512);

    // ---- embed: lane embeds patch pbase+lane, j-quarter jb = wave index
    {
        const int row = lane;
        const int jb  = wv;
        const int p = pbase + row;
        const int b = p / OUTL, ol = p - b * OUTL;
        const float* xp = x + b * LEN + ol;
        float ec[NQ], es[NQ];
#pragma unroll
        for (int q = 0; q < NQ; ++q) {
            float half = xp[q] * 1.5707963267948966f;
            ec[q] = __cosf(half);
            es[q] = __sinf(half);
        }
        float st[64];
        st[0] = (jb & 2 ? es[0] : ec[0]) * (jb & 1 ? es[1] : ec[1]);
#pragma unroll
        for (int q = 2; q <= 7; ++q) {           // wires 2..7 -> j bits 5..0
            const int m = 1 << (7 - q);
#pragma unroll
            for (int jj = (1 << (q - 2)) - 1; jj >= 0; --jj) {
                float v = st[jj * 2 * m];
                st[jj * 2 * m + m] = v * es[q];
                st[jj * 2 * m]     = v * ec[q];
            }
        }
#pragma unroll
        for (int cc = 0; cc < 8; ++cc) {
            uint4 vv;
            vv.x = pk_bf16(st[cc * 8 + 0], st[cc * 8 + 1]);
            vv.y = pk_bf16(st[cc * 8 + 2], st[cc * 8 + 3]);
            vv.z = pk_bf16(st[cc * 8 + 4], st[cc * 8 + 5]);
            vv.w = pk_bf16(st[cc * 8 + 6], st[cc * 8 + 7]);
            int phys = ((jb * 8 + cc) ^ (row & 7)) & 31;
            *(uint4*)((char*)Alds + row * 512 + phys * 16) = vv;
        }
    }
    __syncthreads();

    const int pu = __builtin_popcount(u) & 1;
    const int pw = __builtin_popcount(wv) & 1;
    const float slane = ((pu ^ pw) & 1) ? -1.0f : 1.0f;

#pragma unroll 1
    for (int it = 0; it < 4; ++it) {
        const int c  = cb + ((it + c0) & 3);     // actual channel this iteration
        const int cn = cb + ((it + 1 + c0) & 3); // next channel in staggered order

        f32x4 acc[4][4];
#pragma unroll
        for (int a = 0; a < 4; ++a)
#pragma unroll
            for (int cq = 0; cq < 4; ++cq) acc[a][cq] = (f32x4){0.f, 0.f, 0.f, 0.f};

#pragma unroll
        for (int s = 0; s < 8; ++s) {
            // consume the single B slot with per-rt A fragments
#pragma unroll
            for (int rt = 0; rt < 4; ++rt) {
                int row = rt * 16 + u;
                int phys = ((s * 4 + g) ^ (row & 7)) & 31;
                bf16x8 af = *(const bf16x8*)((const char*)Alds + row * 512 + phys * 16);
#pragma unroll
                for (int ct = 0; ct < 4; ++ct)
                    acc[rt][ct] = __builtin_amdgcn_mfma_f32_16x16x32_bf16(
                        af, *(bf16x8*)&breg[ct], acc[rt][ct], 0, 0, 0);
            }
            // refill the slot for the next staggered phase (WAR-safe)
            const int phn = (s < 7) ? (c * 8 + s + 1) : (cn * 8);
            if (!(it == 3 && s == 7)) {
#pragma unroll
                for (int ct = 0; ct < 4; ++ct)
                    breg[ct] = *(const uint4*)(bbase + (size_t)phn * 8192 + ct * 512);
            }
        }

        // epilogue: parity-grouped signed square (sign folded to one mul),
        // then DPP-rotation reduce over the 16-lane col group
#pragma unroll
        for (int rt = 0; rt < 4; ++rt) {
            f32x4 pe = acc[rt][0] * acc[rt][0];   // ct=0: popc even
            pe += acc[rt][3] * acc[rt][3];        // ct=3: popc even
            f32x4 po = acc[rt][1] * acc[rt][1];   // ct=1: popc odd
            po += acc[rt][2] * acc[rt][2];        // ct=2: popc odd
            f32x4 part = (pe - po) * slane;
            float v0 = part[0], v1 = part[1], v2 = part[2], v3 = part[3];
            v0 = ror_add<8>(ror_add<4>(ror_add<2>(ror_add<1>(v0))));
            v1 = ror_add<8>(ror_add<4>(ror_add<2>(ror_add<1>(v1))));
            v2 = ror_add<8>(ror_add<4>(ror_add<2>(ror_add<1>(v2))));
            v3 = ror_add<8>(ror_add<4>(ror_add<2>(ror_add<1>(v3))));
            if (u == 0) {
                f32x4 vv = (f32x4){v0, v1, v2, v3};
                *(f32x4*)&red[((c & 3) * 4 + wv) * 64 + rt * 16 + g * 4] = vv;
            }
        }
    }

    __syncthreads();
    // final: sum 4 wave-partials, store. 1 output/thread (4ch x 64 rows = 256)
    {
        int chl = tid >> 6, row = tid & 63;
        int ch = cb + chl;
        float o = red[(chl * 4 + 0) * 64 + row] + red[(chl * 4 + 1) * 64 + row] +
                  red[(chl * 4 + 2) * 64 + row] + red[(chl * 4 + 3) * 64 + row];
        int p = pbase + row;
        int b = p / OUTL, ol = p - b * OUTL;
        out[b * (OUTC * OUTL) + ch * OUTL + ol] = o;
    }
}

// ---------------- Fallback: verified direct simulator (213 us)
__global__ __launch_bounds__(256) void qconv_direct(const float* __restrict__ x,
                                                    const float* __restrict__ w,
                                                    float* __restrict__ out) {
    const int lane = threadIdx.x & 63;
    const int wave = threadIdx.x >> 6;
    const int bi   = blockIdx.x;
    const int k    = bi / BLK_PER_CH;
    const int pblk = bi % BLK_PER_CH;
    const int patch = pblk * 64 + wave * 16 + (lane >> 2);
    const int b0 = (lane >> 1) & 1;
    const int b7 = lane & 1;
    const int b  = patch / OUTL;
    const int ol = patch - b * OUTL;
    const float* xp = x + b * LEN + ol;

    float ec[NQ], es[NQ];
#pragma unroll
    for (int q = 0; q < NQ; ++q) {
        float half = xp[q] * 1.5707963267948966f;
        ec[q] = __cosf(half);
        es[q] = __sinf(half);
    }
    float st[64];
    st[0] = (b0 ? es[0] : ec[0]) * (b7 ? es[7] : ec[7]);
#pragma unroll
    for (int q = 1; q <= 6; ++q) {
        const int m = 1 << (6 - q);
#pragma unroll
        for (int j = (1 << (q - 1)) - 1; j >= 0; --j) {
            float v = st[j * 2 * m];
            st[j * 2 * m + m] = v * es[q];
            st[j * 2 * m]     = v * ec[q];
        }
    }
    run_layers(st, w + k * (NLAYERS * NQ), b0, b7);

    float accp = 0.0f, accm = 0.0f;
#pragma unroll
    for (int r = 0; r < 64; ++r) {
        if (__builtin_popcount(r) & 1) accm = fmaf(st[r], st[r], accm);
        else                           accp = fmaf(st[r], st[r], accp);
    }
    float v = accp - accm;
    if (b0 ^ b7) v = -v;
    v += dpp_xor<0xB1>(v);
    v += dpp_xor<0x4E>(v);
    if ((lane & 3) == 0) out[b * (OUTC * OUTL) + k * OUTL + ol] = v;
}

extern "C" void kernel_launch(void* const* d_in, const int* in_sizes, int n_in,
                              void* d_out, int out_size, void* d_ws, size_t ws_size,
                              hipStream_t stream) {
    const float* x = (const float*)d_in[0];   // (128,1,512) f32
    const float* w = (const float*)d_in[1];   // (8,32) f32
    float* out = (float*)d_out;               // (128,8,505) f32

    if (ws_size < (size_t)(8 * 256 * 256 * 2)) {
        qconv_direct<<<dim3(OUTC * BLK_PER_CH), 256, 0, stream>>>(x, w, out);
        return;
    }
    ushort* W2 = (ushort*)d_ws;               // 1 MB bf16, direct-fragment layout
    build_m<<<dim3(32), 256, 0, stream>>>(w, W2);
    qconv_mfma<<<dim3(NBLK * 2), 256, 0, stream>>>(x, W2, out);
}